// Round 9
// baseline (228.237 us; speedup 1.0000x reference)
//
#include <hip/hip_runtime.h>

#define DEVINL __device__ __forceinline__

typedef unsigned short u16;
typedef __attribute__((ext_vector_type(4))) short s16x4;
typedef __attribute__((ext_vector_type(8))) short s16x8;
typedef __attribute__((ext_vector_type(4))) float f32x4;

static constexpr int Bb = 4, Tt = 2048, Cc = 1024, Hh = 16, Dd = 64;
static constexpr int Mm = Bb * Tt;  // 8192
static constexpr int KK = Cc;       // 1024

DEVINL float bf2f(u16 u) { return __uint_as_float(((unsigned)u) << 16); }
DEVINL u16 f2bf(float f) {
  unsigned b = __float_as_uint(f);
  b += 0x7fff + ((b >> 16) & 1);  // RNE
  return (u16)(b >> 16);
}
DEVINL unsigned cvtpk(float lo, float hi) {  // bf16(lo) | bf16(hi)<<16, RNE
  unsigned r;
  asm("v_cvt_pk_bf16_f32 %0, %1, %2" : "=v"(r) : "v"(lo), "v"(hi));
  return r;
}

#define GLDS(gsrc, ldst) \
  __builtin_amdgcn_global_load_lds((const __attribute__((address_space(1))) void*)(gsrc), \
                                   (__attribute__((address_space(3))) void*)(ldst), 16, 0, 0)

// ---------------- f32 -> bf16 convert (x4 vectorized) ----------------
__global__ void cvt_bf16(const float* __restrict__ src, u16* __restrict__ dst, int n4) {
  int i = blockIdx.x * blockDim.x + threadIdx.x;
  int st = gridDim.x * blockDim.x;
  for (int g = i; g < n4; g += st) {
    float4 v = ((const float4*)src)[g];
    uint2 o;
    o.x = (unsigned)f2bf(v.x) | ((unsigned)f2bf(v.y) << 16);
    o.y = (unsigned)f2bf(v.z) | ((unsigned)f2bf(v.w) << 16);
    ((uint2*)dst)[g] = o;
  }
}

// ---------------- 4 weight converts in one launch ----------------
struct Cvt4Args { const float* s[4]; u16* d[4]; };
__global__ void cvt4(Cvt4Args a, int n4) {
  const float* __restrict__ src = a.s[blockIdx.y];
  u16* __restrict__ dst = a.d[blockIdx.y];
  int i = blockIdx.x * blockDim.x + threadIdx.x;
  int st = gridDim.x * blockDim.x;
  for (int g = i; g < n4; g += st) {
    float4 v = ((const float4*)src)[g];
    uint2 o;
    o.x = (unsigned)f2bf(v.x) | ((unsigned)f2bf(v.y) << 16);
    o.y = (unsigned)f2bf(v.z) | ((unsigned)f2bf(v.w) << 16);
    ((uint2*)dst)[g] = o;
  }
}

// ---- shared K-loop for all GEMMs: fixed __shared__ As/Bs, glds staging ----
#define GEMM_PROLOG()                                              \
  const int tid = threadIdx.x, w = tid >> 6, l = tid & 63;         \
  const int lr = l & 15, lg = l >> 4;                              \
  const int m0 = blockIdx.x * 128, n0 = blockIdx.y * 128;          \
  const int wr = w >> 1, wc = w & 1;                               \
  f32x4 zero = {0.f, 0.f, 0.f, 0.f};                               \
  f32x4 acc[4][4];                                                 \
  _Pragma("unroll") for (int i = 0; i < 4; ++i)                    \
      _Pragma("unroll") for (int j = 0; j < 4; ++j) acc[i][j] = zero; \
  const int srow = l >> 3;                                         \
  const int scolsw = ((l & 7) ^ (l >> 3)) * 8;

#define GEMM_KLOOP(Aptr, Wptr)                                                         \
  for (int k0 = 0; k0 < KK; k0 += 64) {                                                \
    _Pragma("unroll") for (int i = 0; i < 4; ++i) {                                    \
      int row = i * 32 + w * 8 + srow;                                                 \
      GLDS(Aptr + (size_t)(m0 + row) * KK + k0 + scolsw, &As[(i * 32 + w * 8) * 64]);  \
      GLDS(Wptr + (size_t)(n0 + row) * KK + k0 + scolsw, &Bs[(i * 32 + w * 8) * 64]);  \
    }                                                                                  \
    __syncthreads();                                                                   \
    _Pragma("unroll") for (int kk = 0; kk < 2; ++kk) {                                 \
      s16x8 af[4], bfr[4];                                                             \
      _Pragma("unroll") for (int i = 0; i < 4; ++i)                                    \
          af[i] = *(const s16x8*)&As[(wr * 64 + i * 16 + lr) * 64 +                    \
                                     ((kk * 32 + lg * 8) ^ ((lr & 7) << 3))];          \
      _Pragma("unroll") for (int j = 0; j < 4; ++j)                                    \
          bfr[j] = *(const s16x8*)&Bs[(wc * 64 + j * 16 + lr) * 64 +                   \
                                      ((kk * 32 + lg * 8) ^ ((lr & 7) << 3))];         \
      _Pragma("unroll") for (int i = 0; i < 4; ++i)                                    \
          _Pragma("unroll") for (int j = 0; j < 4; ++j)                                \
              acc[i][j] =                                                              \
                  __builtin_amdgcn_mfma_f32_16x16x32_bf16(af[i], bfr[j], acc[i][j], 0, 0, 0); \
    }                                                                                  \
    __syncthreads();                                                                   \
  }

// ---------------- Q/K GEMM with fused RoPE epilogue ----------------
// z=0 -> Q (rope + 0.125*log2e scale), z=1 -> K (rope only); out bf16 (B,H,T,D)
__global__ __launch_bounds__(256) void gemm_qk(const u16* __restrict__ A,
                                               const u16* __restrict__ W0,
                                               const u16* __restrict__ W1,
                                               const float* __restrict__ b0,
                                               const float* __restrict__ b1,
                                               const float* __restrict__ rope,
                                               u16* __restrict__ O0, u16* __restrict__ O1) {
  __shared__ __align__(16) u16 As[128 * 64];
  __shared__ __align__(16) u16 Bs[128 * 64];
  const int z = blockIdx.z;
  const u16* __restrict__ Wt = z ? W1 : W0;
  const float* __restrict__ bias = z ? b1 : b0;
  u16* __restrict__ O = z ? O1 : O0;
  const float scl = z ? 1.0f : 0.18033688f;  // 0.125 * log2(e) folded into Q
  GEMM_PROLOG()
  GEMM_KLOOP(A, Wt)
  // epilogue: C/D layout col=lane&15, row=(lane>>4)*4+r. RoPE pairs (d, d^1)
  // live in adjacent lanes (lr, lr^1): shfl_xor(1) exchanges the pair values.
#pragma unroll
  for (int j = 0; j < 4; ++j) {
    int ncol = n0 + wc * 64 + j * 16 + lr;
    float bj = bias[ncol];
    int hh = ncol >> 6, dd = ncol & 63;
    const float sign = (dd & 1) ? 1.0f : -1.0f;
    const float* csp = rope + (dd >> 1) * 2;
#pragma unroll
    for (int i = 0; i < 4; ++i) {
#pragma unroll
      for (int r = 0; r < 4; ++r) {
        int mrow = m0 + wr * 64 + i * 16 + lg * 4 + r;
        int bb2 = mrow >> 11, tt2 = mrow & (Tt - 1);
        float v = acc[i][j][r] + bj;
        float part = __shfl_xor(v, 1);  // partner value (own bias already added)
        float2 cs = *(const float2*)(csp + tt2 * 64);
        float outv = (v * cs.x + sign * part * cs.y) * scl;
        O[(((size_t)bb2 * Hh + hh) * Tt + tt2) * Dd + dd] = f2bf(outv);
      }
    }
  }
}

// ---------------- V GEMM: out bf16 (B,H,D,T) via two-pass LDS transpose ----------------
__global__ __launch_bounds__(256) void gemm_v(const u16* __restrict__ A,
                                              const u16* __restrict__ Wt,
                                              const float* __restrict__ bias,
                                              u16* __restrict__ O) {
  __shared__ __align__(16) u16 As[128 * 64];
  __shared__ __align__(16) u16 Bs[128 * 64];
  __shared__ __align__(16) u16 Ts[128 * 64];  // [ncol_local][mrow_half], slot4-XOR swizzled
  GEMM_PROLOG()
  GEMM_KLOOP(A, Wt)
  const int bb2 = m0 >> 11, tloc = m0 & (Tt - 1);
#pragma unroll
  for (int p = 0; p < 2; ++p) {
    if (p) __syncthreads();
    if (wr == p) {
#pragma unroll
      for (int j = 0; j < 4; ++j) {
        int ncl = wc * 64 + j * 16 + lr;
        float bj = bias[n0 + ncl];
        int xw = (ncl & 3) << 2;
#pragma unroll
        for (int i = 0; i < 4; ++i) {
          s16x4 pk;
#pragma unroll
          for (int r = 0; r < 4; ++r) pk[r] = (short)f2bf(acc[i][j][r] + bj);
          *(s16x4*)&Ts[ncl * 64 + (((i * 4 + lg) ^ xw) << 2)] = pk;
        }
      }
    }
    __syncthreads();
    // all threads: read Ts and store coalesced along T (128B per row-half)
    const int rn = tid >> 3, t8 = tid & 7;
#pragma unroll
    for (int it = 0; it < 4; ++it) {
      int rown = it * 32 + rn;  // ncol_local
      int slot = (t8 * 2) ^ ((rown & 3) << 2);
      s16x8 v = *(const s16x8*)&Ts[rown * 64 + slot * 4];
      int ncol = n0 + rown;
      int hh2 = ncol >> 6, dd = ncol & 63;
      *(s16x8*)&O[(((size_t)bb2 * Hh + hh2) * Dd + dd) * Tt + tloc + p * 64 + t8 * 8] = v;
    }
  }
}

// ---------------- projection GEMM: out f32 flat (M x C) ----------------
__global__ __launch_bounds__(256) void gemm_proj(const u16* __restrict__ A,
                                                 const u16* __restrict__ Wt,
                                                 const float* __restrict__ bias,
                                                 float* __restrict__ O) {
  __shared__ __align__(16) u16 As[128 * 64];
  __shared__ __align__(16) u16 Bs[128 * 64];
  GEMM_PROLOG()
  GEMM_KLOOP(A, Wt)
#pragma unroll
  for (int j = 0; j < 4; ++j) {
    int ncol = n0 + wc * 64 + j * 16 + lr;
    float bj = bias[ncol];
#pragma unroll
    for (int i = 0; i < 4; ++i) {
#pragma unroll
      for (int r = 0; r < 4; ++r) {
        int mrow = m0 + wr * 64 + i * 16 + lg * 4 + r;
        O[(size_t)mrow * Cc + ncol] = acc[i][j][r] + bj;
      }
    }
  }
}

// ---------------- causal flash attention (merged q-tile pair) ----------------
// Swapped QK^T and swapped PV (softmax state lane-local, q=lr). KVBLK=64,
// double-buffered glds staging, counted vmcnt + raw barriers, XCD swizzle.
// Block owns q-tiles {qt, 31-qt}; ONE kt loop stages K/V once and computes
// both tiles on the overlap (kt <= qt) -> ~2x MFMA per barrier there.
__global__ __launch_bounds__(256, 4) void attn_kernel(const u16* __restrict__ Q,
                                                      const u16* __restrict__ K,
                                                      const u16* __restrict__ VTg,
                                                      u16* __restrict__ Out) {
  __shared__ __align__(16) u16 Ks[2][64 * 64];   // [key][d] swizzled c8^=(key&7)
  __shared__ __align__(16) u16 VTs[2][64 * 64];  // [d][key] swizzled c8^=(d&7)
  __shared__ __align__(16) u16 Ps[4 * 16 * 32];  // per-wave [q][32key], slot8 ^= psw
  const int tid = threadIdx.x, w = tid >> 6, l = tid & 63;
  const int lr = l & 15, lg = l >> 4;
  // XCD swizzle: all 16 blocks of a head land on one XCD (L2-resident K/V).
  const int n = blockIdx.x + 16 * blockIdx.y;
  const int bh = ((n & 7) << 3) + (n >> 7);
  const int qt = (n >> 3) & 15;  // light q-tile; heavy = 31-qt
  const int qtH = 31 - qt;
  const size_t base = (size_t)bh * Tt * Dd;
  const u16* Qp = Q + base;
  const u16* Kp = K + base;
  const u16* Vp = VTg + base;  // (D, T) per bh
  const int bb2 = bh >> 4, hh = bh & 15;
  const float NEG = -3.0e9f;
  f32x4 zero = {0.f, 0.f, 0.f, 0.f};
  const int krow_l = l >> 3, kc8sw = ((l & 7) ^ (l >> 3)) * 8;  // glds lane constants
  const int psw = (lr >> 1) & 3;  // P swizzle for this lane's q-row

  // per-q-tile state
  const int qgL = qt * 64 + w * 16 + lr, qgH = qtH * 64 + w * 16 + lr;
  s16x8 qfL[2], qfH[2];
  qfL[0] = *(const s16x8*)(Qp + (size_t)qgL * 64 + lg * 8);
  qfL[1] = *(const s16x8*)(Qp + (size_t)qgL * 64 + 32 + lg * 8);
  qfH[0] = *(const s16x8*)(Qp + (size_t)qgH * 64 + lg * 8);
  qfH[1] = *(const s16x8*)(Qp + (size_t)qgH * 64 + 32 + lg * 8);
  f32x4 oL[4] = {zero, zero, zero, zero};
  f32x4 oH[4] = {zero, zero, zero, zero};
  float mL = -3e38f, lsL = 0.f, mH = -3e38f, lsH = 0.f;

  auto stage = [&](int kt, int buf) {
    const int kk0 = kt * 64;
#pragma unroll
    for (int i = 0; i < 2; ++i) {
      int row = i * 32 + w * 8 + krow_l;  // key row for K, d row for VT
      GLDS(Kp + (size_t)(kk0 + row) * 64 + kc8sw, &Ks[buf][(i * 32 + w * 8) * 64]);
      GLDS(Vp + (size_t)row * Tt + kk0 + kc8sw, &VTs[buf][(i * 32 + w * 8) * 64]);
    }
  };

  // one 64-key tile for one q-tile's state
  auto tile = [&](int kt, int buf, f32x4 (&o)[4], const s16x8 (&qf)[2],
                  float& m, float& lsum, int qg, bool diag) {
    float pv[4][4];
    __builtin_amdgcn_s_setprio(1);
#pragma unroll
    for (int cf = 0; cf < 4; ++cf) {
      f32x4 s = zero;
#pragma unroll
      for (int kf = 0; kf < 2; ++kf) {
        s16x8 kb = *(const s16x8*)&Ks[buf][(cf * 16 + lr) * 64 +
                                          (((kf * 4 + lg) ^ (lr & 7)) << 3)];
        s = __builtin_amdgcn_mfma_f32_16x16x32_bf16(kb, qf[kf], s, 0, 0, 0);
      }
      if (diag) {
        int key0 = kt * 64 + cf * 16 + lg * 4;
#pragma unroll
        for (int r = 0; r < 4; ++r) pv[cf][r] = (key0 + r <= qg) ? s[r] : NEG;
      } else {
#pragma unroll
        for (int r = 0; r < 4; ++r) pv[cf][r] = s[r];
      }
    }
    __builtin_amdgcn_s_setprio(0);
    // online softmax: stats lane-local for q = lr (keys split across lg)
    float t0 = fmaxf(fmaxf(pv[0][0], pv[0][1]), fmaxf(pv[0][2], pv[0][3]));
#pragma unroll
    for (int cf = 1; cf < 4; ++cf) {
      float tc = fmaxf(fmaxf(pv[cf][0], pv[cf][1]), fmaxf(pv[cf][2], pv[cf][3]));
      t0 = fmaxf(t0, tc);
    }
    t0 = fmaxf(t0, __shfl_xor(t0, 16));
    float tm = fmaxf(t0, __shfl_xor(t0, 32));
    int stable = tm <= m + 11.5f;  // defer-max (log2 domain, ~e^8)
    if (!__all(stable)) {
      float mn = fmaxf(m, tm);
      float fsc = __builtin_amdgcn_exp2f(m - mn);
      lsum *= fsc;
      m = mn;
#pragma unroll
      for (int jf = 0; jf < 4; ++jf) {
        o[jf][0] *= fsc; o[jf][1] *= fsc; o[jf][2] *= fsc; o[jf][3] *= fsc;
      }
    }
    float psum = 0.f;
#pragma unroll
    for (int cf = 0; cf < 4; ++cf)
#pragma unroll
      for (int r = 0; r < 4; ++r) {
        float p = __builtin_amdgcn_exp2f(pv[cf][r] - m);
        pv[cf][r] = p;
        psum += p;
      }
    psum += __shfl_xor(psum, 16);
    psum += __shfl_xor(psum, 32);
    lsum += psum;
    // PV in 2 chunks of 32 keys: packed P->LDS (b32), A=V^T, B=P^T
#pragma unroll
    for (int kk = 0; kk < 2; ++kk) {
#pragma unroll
      for (int c = 0; c < 2; ++c) {
        int cf = kk * 2 + c;
        unsigned w0 = cvtpk(pv[cf][0], pv[cf][1]);
        unsigned w1 = cvtpk(pv[cf][2], pv[cf][3]);
        int col0 = c * 16 + lg * 4;  // key_local, u32-aligned
        int idx = w * 512 + lr * 32 + ((((col0 >> 3) ^ psw)) << 3) + (col0 & 7);
        *(unsigned*)&Ps[idx] = w0;
        *(unsigned*)&Ps[idx + 2] = w1;
      }
      s16x8 pa = *(const s16x8*)&Ps[w * 512 + lr * 32 + ((lg ^ psw) << 3)];
      __builtin_amdgcn_s_setprio(1);
#pragma unroll
      for (int jf = 0; jf < 4; ++jf) {
        s16x8 vb = *(const s16x8*)&VTs[buf][(jf * 16 + lr) * 64 +
                                           (((kk * 4 + lg) ^ (lr & 7)) << 3)];
        o[jf] = __builtin_amdgcn_mfma_f32_16x16x32_bf16(vb, pa, o[jf], 0, 0, 0);
      }
      __builtin_amdgcn_s_setprio(0);
    }
  };

  const int htiles = qtH + 1;  // 32 - qt stages cover BOTH q-tiles
  stage(0, 0);
  for (int kt = 0; kt < htiles; ++kt) {
    const int buf = kt & 1;
    if (kt + 1 < htiles) {
      stage(kt + 1, buf ^ 1);  // next tile's loads in flight across this compute
      asm volatile("s_waitcnt vmcnt(4)" ::: "memory");  // wait ONLY current tile
    } else {
      asm volatile("s_waitcnt vmcnt(0)" ::: "memory");
    }
    __builtin_amdgcn_s_barrier();
    __builtin_amdgcn_sched_barrier(0);
    tile(kt, buf, oH, qfH, mH, lsH, qgH, kt == qtH);
    if (kt <= qt)  // wave-uniform
      tile(kt, buf, oL, qfL, mL, lsL, qgL, kt == qt);
    __builtin_amdgcn_sched_barrier(0);
    __builtin_amdgcn_s_barrier();  // buf may be re-staged next iteration
  }
  // epilogue: O^T[d][q=lr]; 4x 8B packed stores per tile, all lane-local
  {
    float linv = 1.0f / lsL;
    u16* orow = Out + ((size_t)(bb2 * Tt + qgL)) * Cc + hh * 64 + lg * 4;
#pragma unroll
    for (int jf = 0; jf < 4; ++jf) {
      uint2 pk;
      pk.x = cvtpk(oL[jf][0] * linv, oL[jf][1] * linv);
      pk.y = cvtpk(oL[jf][2] * linv, oL[jf][3] * linv);
      *(uint2*)&orow[jf * 16] = pk;
    }
  }
  {
    float linv = 1.0f / lsH;
    u16* orow = Out + ((size_t)(bb2 * Tt + qgH)) * Cc + hh * 64 + lg * 4;
#pragma unroll
    for (int jf = 0; jf < 4; ++jf) {
      uint2 pk;
      pk.x = cvtpk(oH[jf][0] * linv, oH[jf][1] * linv);
      pk.y = cvtpk(oH[jf][2] * linv, oH[jf][3] * linv);
      *(uint2*)&orow[jf * 16] = pk;
    }
  }
}

extern "C" void kernel_launch(void* const* d_in, const int* in_sizes, int n_in,
                              void* d_out, int out_size, void* d_ws, size_t ws_size,
                              hipStream_t stream) {
  (void)in_sizes; (void)n_in; (void)out_size; (void)ws_size;
  const float* x = (const float*)d_in[0];
  const float* Wq = (const float*)d_in[1];
  const float* bq = (const float*)d_in[2];
  const float* Wk = (const float*)d_in[3];
  const float* bk = (const float*)d_in[4];
  const float* Wv = (const float*)d_in[5];
  const float* bv = (const float*)d_in[6];
  const float* Wp = (const float*)d_in[7];
  const float* bp = (const float*)d_in[8];
  const float* rope = (const float*)d_in[9];

  char* ws = (char*)d_ws;
  const size_t MB = 1024 * 1024;
  u16* xb  = (u16*)(ws + 0);        // 16 MB: x as bf16 (8192x1024)
  u16* wqb = (u16*)(ws + 16 * MB);  // 2 MB each
  u16* wkb = (u16*)(ws + 18 * MB);
  u16* wvb = (u16*)(ws + 20 * MB);
  u16* wpb = (u16*)(ws + 22 * MB);
  u16* qb  = (u16*)(ws + 24 * MB);  // 16 MB each; q,k: (B,H,T,D)
  u16* kb  = (u16*)(ws + 40 * MB);
  u16* vt  = (u16*)(ws + 56 * MB);  // V written directly transposed (B,H,D,T)
  u16* att = (u16*)(ws + 72 * MB);  // 16 MB, (B,T,C) bf16 -> ends 88 MB

  cvt_bf16<<<2048, 256, 0, stream>>>(x, xb, (Mm * Cc) / 4);
  Cvt4Args ca;
  ca.s[0] = Wq; ca.s[1] = Wk; ca.s[2] = Wv; ca.s[3] = Wp;
  ca.d[0] = wqb; ca.d[1] = wkb; ca.d[2] = wvb; ca.d[3] = wpb;
  cvt4<<<dim3(256, 4), 256, 0, stream>>>(ca, (Cc * Cc) / 4);

  gemm_qk<<<dim3(Mm / 128, Cc / 128, 2), 256, 0, stream>>>(xb, wqb, wkb, bq, bk, rope, qb, kb);
  gemm_v<<<dim3(Mm / 128, Cc / 128), 256, 0, stream>>>(xb, wvb, bv, vt);

  attn_kernel<<<dim3(16, Bb * Hh), 256, 0, stream>>>(qb, kb, vt, att);

  gemm_proj<<<dim3(Mm / 128, Cc / 128), 256, 0, stream>>>(att, wpb, bp, (float*)d_out);
}

// Round 10
// 174.706 us; speedup vs baseline: 1.3064x; 1.3064x over previous
//
#include <hip/hip_runtime.h>

#define DEVINL __device__ __forceinline__

typedef unsigned short u16;
typedef __attribute__((ext_vector_type(4))) short s16x4;
typedef __attribute__((ext_vector_type(8))) short s16x8;
typedef __attribute__((ext_vector_type(4))) float f32x4;

static constexpr int Bb = 4, Tt = 2048, Cc = 1024, Hh = 16, Dd = 64;
static constexpr int Mm = Bb * Tt;  // 8192
static constexpr int KK = Cc;       // 1024

DEVINL float bf2f(u16 u) { return __uint_as_float(((unsigned)u) << 16); }
DEVINL u16 f2bf(float f) {
  unsigned b = __float_as_uint(f);
  b += 0x7fff + ((b >> 16) & 1);  // RNE
  return (u16)(b >> 16);
}
DEVINL unsigned cvtpk(float lo, float hi) {  // bf16(lo) | bf16(hi)<<16, RNE
  unsigned r;
  asm("v_cvt_pk_bf16_f32 %0, %1, %2" : "=v"(r) : "v"(lo), "v"(hi));
  return r;
}

#define GLDS(gsrc, ldst) \
  __builtin_amdgcn_global_load_lds((const __attribute__((address_space(1))) void*)(gsrc), \
                                   (__attribute__((address_space(3))) void*)(ldst), 16, 0, 0)

// ---------------- f32 -> bf16 convert (x4 vectorized) ----------------
__global__ void cvt_bf16(const float* __restrict__ src, u16* __restrict__ dst, int n4) {
  int i = blockIdx.x * blockDim.x + threadIdx.x;
  int st = gridDim.x * blockDim.x;
  for (int g = i; g < n4; g += st) {
    float4 v = ((const float4*)src)[g];
    uint2 o;
    o.x = (unsigned)f2bf(v.x) | ((unsigned)f2bf(v.y) << 16);
    o.y = (unsigned)f2bf(v.z) | ((unsigned)f2bf(v.w) << 16);
    ((uint2*)dst)[g] = o;
  }
}

// ---------------- 4 weight converts in one launch ----------------
struct Cvt4Args { const float* s[4]; u16* d[4]; };
__global__ void cvt4(Cvt4Args a, int n4) {
  const float* __restrict__ src = a.s[blockIdx.y];
  u16* __restrict__ dst = a.d[blockIdx.y];
  int i = blockIdx.x * blockDim.x + threadIdx.x;
  int st = gridDim.x * blockDim.x;
  for (int g = i; g < n4; g += st) {
    float4 v = ((const float4*)src)[g];
    uint2 o;
    o.x = (unsigned)f2bf(v.x) | ((unsigned)f2bf(v.y) << 16);
    o.y = (unsigned)f2bf(v.z) | ((unsigned)f2bf(v.w) << 16);
    ((uint2*)dst)[g] = o;
  }
}

// ---- shared K-loop for all GEMMs: double-buffered glds staging, counted vmcnt ----
#define GEMM_PROLOG()                                              \
  const int tid = threadIdx.x, w = tid >> 6, l = tid & 63;         \
  const int lr = l & 15, lg = l >> 4;                              \
  const int m0 = blockIdx.x * 128, n0 = blockIdx.y * 128;          \
  const int wr = w >> 1, wc = w & 1;                               \
  f32x4 zero = {0.f, 0.f, 0.f, 0.f};                               \
  f32x4 acc[4][4];                                                 \
  _Pragma("unroll") for (int i = 0; i < 4; ++i)                    \
      _Pragma("unroll") for (int j = 0; j < 4; ++j) acc[i][j] = zero; \
  const int srow = l >> 3;                                         \
  const int scolsw = ((l & 7) ^ (l >> 3)) * 8;

#define GEMM_STAGE(Aptr, Wptr, k0, buf)                                                  \
  _Pragma("unroll") for (int i = 0; i < 4; ++i) {                                        \
    int row = i * 32 + w * 8 + srow;                                                     \
    GLDS(Aptr + (size_t)(m0 + row) * KK + (k0) + scolsw, &As[buf][(i * 32 + w * 8) * 64]); \
    GLDS(Wptr + (size_t)(n0 + row) * KK + (k0) + scolsw, &Bs[buf][(i * 32 + w * 8) * 64]); \
  }

#define GEMM_KLOOP_DB(Aptr, Wptr)                                                        \
  GEMM_STAGE(Aptr, Wptr, 0, 0)                                                           \
  for (int k0 = 0; k0 < KK; k0 += 64) {                                                  \
    const int buf = (k0 >> 6) & 1;                                                       \
    if (k0 + 64 < KK) {                                                                  \
      GEMM_STAGE(Aptr, Wptr, k0 + 64, buf ^ 1)                                           \
      asm volatile("s_waitcnt vmcnt(8)" ::: "memory"); /* current tile done */           \
    } else {                                                                             \
      asm volatile("s_waitcnt vmcnt(0)" ::: "memory");                                   \
    }                                                                                    \
    __builtin_amdgcn_s_barrier();                                                        \
    __builtin_amdgcn_sched_barrier(0);                                                   \
    _Pragma("unroll") for (int kk = 0; kk < 2; ++kk) {                                   \
      s16x8 af[4], bfr[4];                                                               \
      _Pragma("unroll") for (int i = 0; i < 4; ++i)                                      \
          af[i] = *(const s16x8*)&As[buf][(wr * 64 + i * 16 + lr) * 64 +                 \
                                         ((kk * 32 + lg * 8) ^ ((lr & 7) << 3))];        \
      _Pragma("unroll") for (int j = 0; j < 4; ++j)                                      \
          bfr[j] = *(const s16x8*)&Bs[buf][(wc * 64 + j * 16 + lr) * 64 +                \
                                          ((kk * 32 + lg * 8) ^ ((lr & 7) << 3))];       \
      _Pragma("unroll") for (int i = 0; i < 4; ++i)                                      \
          _Pragma("unroll") for (int j = 0; j < 4; ++j)                                  \
              acc[i][j] =                                                                \
                  __builtin_amdgcn_mfma_f32_16x16x32_bf16(af[i], bfr[j], acc[i][j], 0, 0, 0); \
    }                                                                                    \
    __builtin_amdgcn_sched_barrier(0);                                                   \
    __builtin_amdgcn_s_barrier(); /* all reads done before next stage overwrites */      \
  }

// ---------------- Q/K GEMM with fused RoPE epilogue ----------------
// z=0 -> Q (rope + 0.125*log2e scale), z=1 -> K (rope only); out bf16 (B,H,T,D)
__global__ __launch_bounds__(256) void gemm_qk(const u16* __restrict__ A,
                                               const u16* __restrict__ W0,
                                               const u16* __restrict__ W1,
                                               const float* __restrict__ b0,
                                               const float* __restrict__ b1,
                                               const float* __restrict__ rope,
                                               u16* __restrict__ O0, u16* __restrict__ O1) {
  __shared__ __align__(16) u16 As[2][128 * 64];
  __shared__ __align__(16) u16 Bs[2][128 * 64];
  const int z = blockIdx.z;
  const u16* __restrict__ Wt = z ? W1 : W0;
  const float* __restrict__ bias = z ? b1 : b0;
  u16* __restrict__ O = z ? O1 : O0;
  const float scl = z ? 1.0f : 0.18033688f;  // 0.125 * log2(e) folded into Q
  GEMM_PROLOG()
  GEMM_KLOOP_DB(A, Wt)
  // epilogue: C/D layout col=lane&15, row=(lane>>4)*4+r. RoPE pairs (d, d^1)
  // live in adjacent lanes (lr, lr^1): shfl_xor(1) exchanges the pair values.
#pragma unroll
  for (int j = 0; j < 4; ++j) {
    int ncol = n0 + wc * 64 + j * 16 + lr;
    float bj = bias[ncol];
    int hh = ncol >> 6, dd = ncol & 63;
    const float sign = (dd & 1) ? 1.0f : -1.0f;
    const float* csp = rope + (dd >> 1) * 2;
#pragma unroll
    for (int i = 0; i < 4; ++i) {
#pragma unroll
      for (int r = 0; r < 4; ++r) {
        int mrow = m0 + wr * 64 + i * 16 + lg * 4 + r;
        int bb2 = mrow >> 11, tt2 = mrow & (Tt - 1);
        float v = acc[i][j][r] + bj;
        float part = __shfl_xor(v, 1);  // partner value (own bias already added)
        float2 cs = *(const float2*)(csp + tt2 * 64);
        float outv = (v * cs.x + sign * part * cs.y) * scl;
        O[(((size_t)bb2 * Hh + hh) * Tt + tt2) * Dd + dd] = f2bf(outv);
      }
    }
  }
}

// ---------------- V GEMM: out bf16 (B,H,D,T) via two-pass LDS transpose ----------------
__global__ __launch_bounds__(256) void gemm_v(const u16* __restrict__ A,
                                              const u16* __restrict__ Wt,
                                              const float* __restrict__ bias,
                                              u16* __restrict__ O) {
  __shared__ __align__(16) u16 As[2][128 * 64];
  __shared__ __align__(16) u16 Bs[2][128 * 64];
  __shared__ __align__(16) u16 Ts[128 * 64];  // [ncol_local][mrow_half], slot4-XOR swizzled
  GEMM_PROLOG()
  GEMM_KLOOP_DB(A, Wt)
  const int bb2 = m0 >> 11, tloc = m0 & (Tt - 1);
#pragma unroll
  for (int p = 0; p < 2; ++p) {
    if (p) __syncthreads();
    if (wr == p) {
#pragma unroll
      for (int j = 0; j < 4; ++j) {
        int ncl = wc * 64 + j * 16 + lr;
        float bj = bias[n0 + ncl];
        int xw = (ncl & 3) << 2;
#pragma unroll
        for (int i = 0; i < 4; ++i) {
          s16x4 pk;
#pragma unroll
          for (int r = 0; r < 4; ++r) pk[r] = (short)f2bf(acc[i][j][r] + bj);
          *(s16x4*)&Ts[ncl * 64 + (((i * 4 + lg) ^ xw) << 2)] = pk;
        }
      }
    }
    __syncthreads();
    // all threads: read Ts and store coalesced along T (128B per row-half)
    const int rn = tid >> 3, t8 = tid & 7;
#pragma unroll
    for (int it = 0; it < 4; ++it) {
      int rown = it * 32 + rn;  // ncol_local
      int slot = (t8 * 2) ^ ((rown & 3) << 2);
      s16x8 v = *(const s16x8*)&Ts[rown * 64 + slot * 4];
      int ncol = n0 + rown;
      int hh2 = ncol >> 6, dd = ncol & 63;
      *(s16x8*)&O[(((size_t)bb2 * Hh + hh2) * Dd + dd) * Tt + tloc + p * 64 + t8 * 8] = v;
    }
  }
}

// ---------------- projection GEMM: out f32 flat (M x C) ----------------
__global__ __launch_bounds__(256) void gemm_proj(const u16* __restrict__ A,
                                                 const u16* __restrict__ Wt,
                                                 const float* __restrict__ bias,
                                                 float* __restrict__ O) {
  __shared__ __align__(16) u16 As[2][128 * 64];
  __shared__ __align__(16) u16 Bs[2][128 * 64];
  GEMM_PROLOG()
  GEMM_KLOOP_DB(A, Wt)
#pragma unroll
  for (int j = 0; j < 4; ++j) {
    int ncol = n0 + wc * 64 + j * 16 + lr;
    float bj = bias[ncol];
#pragma unroll
    for (int i = 0; i < 4; ++i) {
#pragma unroll
      for (int r = 0; r < 4; ++r) {
        int mrow = m0 + wr * 64 + i * 16 + lg * 4 + r;
        O[(size_t)mrow * Cc + ncol] = acc[i][j][r] + bj;
      }
    }
  }
}

// ---------------- causal flash attention (round-8 version, known-good) ----------------
// Swapped QK^T and swapped PV (all softmax state lane-local, q=lr).
// KVBLK=64, double-buffered glds K/V staging with counted vmcnt + raw barriers,
// XCD-aware block swizzle (16 q-blocks of a head share one XCD L2).
__global__ __launch_bounds__(256, 4) void attn_kernel(const u16* __restrict__ Q,
                                                      const u16* __restrict__ K,
                                                      const u16* __restrict__ VTg,
                                                      u16* __restrict__ Out) {
  __shared__ __align__(16) u16 Ks[2][64 * 64];   // [key][d] swizzled c8^=(key&7)
  __shared__ __align__(16) u16 VTs[2][64 * 64];  // [d][key] swizzled c8^=(d&7)
  __shared__ __align__(16) u16 Ps[4 * 16 * 32];  // per-wave [q][32key], slot8 ^= psw
  const int tid = threadIdx.x, w = tid >> 6, l = tid & 63;
  const int lr = l & 15, lg = l >> 4;
  // XCD swizzle: flat n -> (bh, qpair) s.t. all 16 q-blocks of a head hit one XCD.
  const int n = blockIdx.x + 16 * blockIdx.y;
  const int bh = ((n & 7) << 3) + (n >> 7);
  const int qpair = (n >> 3) & 15;
  const size_t base = (size_t)bh * Tt * Dd;
  const u16* Qp = Q + base;
  const u16* Kp = K + base;
  const u16* Vp = VTg + base;  // (D, T) per bh
  const int bb2 = bh >> 4, hh = bh & 15;
  const float NEG = -3.0e9f;
  f32x4 zero = {0.f, 0.f, 0.f, 0.f};
  const int krow_l = l >> 3, kc8sw = ((l & 7) ^ (l >> 3)) * 8;  // glds lane constants
  const int psw = (lr >> 1) & 3;  // P swizzle for this lane's q-row

  auto process = [&](int qt) {
    const int qb0 = qt * 64;
    const int qrow = qb0 + w * 16 + lr;
    const int qg = qrow;  // this lane's q (column of both C-frags)
    s16x8 qf[2];
    qf[0] = *(const s16x8*)(Qp + (size_t)qrow * 64 + lg * 8);
    qf[1] = *(const s16x8*)(Qp + (size_t)qrow * 64 + 32 + lg * 8);
    f32x4 o[4] = {zero, zero, zero, zero};  // O^T[d=jf*16+lg*4+r][q=lr]
    float m = -3e38f, lsum = 0.f;
    const int ktiles = qt + 1;
    // stage: 4 glds per wave (2 K rows-of-32 + 2 VT rows-of-32)
    auto stage = [&](int kt, int buf) {
      const int kk0 = kt * 64;
#pragma unroll
      for (int i = 0; i < 2; ++i) {
        int row = i * 32 + w * 8 + krow_l;  // key row for K, d row for VT
        GLDS(Kp + (size_t)(kk0 + row) * 64 + kc8sw, &Ks[buf][(i * 32 + w * 8) * 64]);
        GLDS(Vp + (size_t)row * Tt + kk0 + kc8sw, &VTs[buf][(i * 32 + w * 8) * 64]);
      }
    };
    stage(0, 0);
    for (int kt = 0; kt < ktiles; ++kt) {
      const int buf = kt & 1;
      if (kt + 1 < ktiles) {
        stage(kt + 1, buf ^ 1);  // next tile's loads in flight across this compute
        asm volatile("s_waitcnt vmcnt(4)" ::: "memory");  // wait ONLY current tile
      } else {
        asm volatile("s_waitcnt vmcnt(0)" ::: "memory");
      }
      __builtin_amdgcn_s_barrier();
      __builtin_amdgcn_sched_barrier(0);
      // ---- QK^T swapped: C[key][q]; lane holds keys cf*16+lg*4+r for q=lr
      float pv[4][4];
      const int diag = (kt == ktiles - 1);
      __builtin_amdgcn_s_setprio(1);
#pragma unroll
      for (int cf = 0; cf < 4; ++cf) {
        f32x4 s = zero;
#pragma unroll
        for (int kf = 0; kf < 2; ++kf) {
          s16x8 kb = *(const s16x8*)&Ks[buf][(cf * 16 + lr) * 64 +
                                            (((kf * 4 + lg) ^ (lr & 7)) << 3)];
          s = __builtin_amdgcn_mfma_f32_16x16x32_bf16(kb, qf[kf], s, 0, 0, 0);
        }
        if (diag) {
          int key0 = kt * 64 + cf * 16 + lg * 4;
#pragma unroll
          for (int r = 0; r < 4; ++r) pv[cf][r] = (key0 + r <= qg) ? s[r] : NEG;
        } else {
#pragma unroll
          for (int r = 0; r < 4; ++r) pv[cf][r] = s[r];
        }
      }
      __builtin_amdgcn_s_setprio(0);
      // ---- online softmax: stats lane-local for q = lr (replicated across lg)
      float t0 = fmaxf(fmaxf(pv[0][0], pv[0][1]), fmaxf(pv[0][2], pv[0][3]));
#pragma unroll
      for (int cf = 1; cf < 4; ++cf) {
        float tc = fmaxf(fmaxf(pv[cf][0], pv[cf][1]), fmaxf(pv[cf][2], pv[cf][3]));
        t0 = fmaxf(t0, tc);
      }
      t0 = fmaxf(t0, __shfl_xor(t0, 16));
      float tm = fmaxf(t0, __shfl_xor(t0, 32));
      int stable = tm <= m + 11.5f;  // defer-max (log2 domain, ~e^8)
      if (!__all(stable)) {
        float mn = fmaxf(m, tm);
        float fsc = __builtin_amdgcn_exp2f(m - mn);
        lsum *= fsc;
        m = mn;
#pragma unroll
        for (int jf = 0; jf < 4; ++jf) {
          o[jf][0] *= fsc; o[jf][1] *= fsc; o[jf][2] *= fsc; o[jf][3] *= fsc;
        }
      }
      float psum = 0.f;
#pragma unroll
      for (int cf = 0; cf < 4; ++cf)
#pragma unroll
        for (int r = 0; r < 4; ++r) {
          float p = __builtin_amdgcn_exp2f(pv[cf][r] - m);
          pv[cf][r] = p;
          psum += p;
        }
      psum += __shfl_xor(psum, 16);
      psum += __shfl_xor(psum, 32);
      lsum += psum;
      // ---- PV in 2 chunks of 32 keys: packed P->LDS (b32), A=V^T, B=P^T
#pragma unroll
      for (int kk = 0; kk < 2; ++kk) {
#pragma unroll
        for (int c = 0; c < 2; ++c) {
          int cf = kk * 2 + c;
          unsigned w0 = cvtpk(pv[cf][0], pv[cf][1]);
          unsigned w1 = cvtpk(pv[cf][2], pv[cf][3]);
          int col0 = c * 16 + lg * 4;  // key_local, u32-aligned
          int idx = w * 512 + lr * 32 + ((((col0 >> 3) ^ psw)) << 3) + (col0 & 7);
          *(unsigned*)&Ps[idx] = w0;
          *(unsigned*)&Ps[idx + 2] = w1;
        }
        s16x8 pa = *(const s16x8*)&Ps[w * 512 + lr * 32 + ((lg ^ psw) << 3)];
        __builtin_amdgcn_s_setprio(1);
#pragma unroll
        for (int jf = 0; jf < 4; ++jf) {
          s16x8 vb = *(const s16x8*)&VTs[buf][(jf * 16 + lr) * 64 +
                                             (((kk * 4 + lg) ^ (lr & 7)) << 3)];
          o[jf] = __builtin_amdgcn_mfma_f32_16x16x32_bf16(vb, pa, o[jf], 0, 0, 0);
        }
        __builtin_amdgcn_s_setprio(0);
      }
      __builtin_amdgcn_sched_barrier(0);
      __builtin_amdgcn_s_barrier();  // buf may be re-staged next iteration
    }
    // ---- epilogue: O^T[d][q=lr]; 4x 8B packed stores, all lane-local
    float linv = 1.0f / lsum;
    int tq = qb0 + w * 16 + lr;
    u16* orow = Out + ((size_t)(bb2 * Tt + tq)) * Cc + hh * 64 + lg * 4;
#pragma unroll
    for (int jf = 0; jf < 4; ++jf) {
      uint2 pk;
      pk.x = cvtpk(o[jf][0] * linv, o[jf][1] * linv);
      pk.y = cvtpk(o[jf][2] * linv, o[jf][3] * linv);
      *(uint2*)&orow[jf * 16] = pk;
    }
  };

  process(qpair);        // light q-tile
  process(31 - qpair);   // heavy q-tile (total 33 k-tiles, balanced)
}

extern "C" void kernel_launch(void* const* d_in, const int* in_sizes, int n_in,
                              void* d_out, int out_size, void* d_ws, size_t ws_size,
                              hipStream_t stream) {
  (void)in_sizes; (void)n_in; (void)out_size; (void)ws_size;
  const float* x = (const float*)d_in[0];
  const float* Wq = (const float*)d_in[1];
  const float* bq = (const float*)d_in[2];
  const float* Wk = (const float*)d_in[3];
  const float* bk = (const float*)d_in[4];
  const float* Wv = (const float*)d_in[5];
  const float* bv = (const float*)d_in[6];
  const float* Wp = (const float*)d_in[7];
  const float* bp = (const float*)d_in[8];
  const float* rope = (const float*)d_in[9];

  char* ws = (char*)d_ws;
  const size_t MB = 1024 * 1024;
  u16* xb  = (u16*)(ws + 0);        // 16 MB: x as bf16 (8192x1024)
  u16* wqb = (u16*)(ws + 16 * MB);  // 2 MB each
  u16* wkb = (u16*)(ws + 18 * MB);
  u16* wvb = (u16*)(ws + 20 * MB);
  u16* wpb = (u16*)(ws + 22 * MB);
  u16* qb  = (u16*)(ws + 24 * MB);  // 16 MB each; q,k: (B,H,T,D)
  u16* kb  = (u16*)(ws + 40 * MB);
  u16* vt  = (u16*)(ws + 56 * MB);  // V written directly transposed (B,H,D,T)
  u16* att = (u16*)(ws + 72 * MB);  // 16 MB, (B,T,C) bf16 -> ends 88 MB

  cvt_bf16<<<2048, 256, 0, stream>>>(x, xb, (Mm * Cc) / 4);
  Cvt4Args ca;
  ca.s[0] = Wq; ca.s[1] = Wk; ca.s[2] = Wv; ca.s[3] = Wp;
  ca.d[0] = wqb; ca.d[1] = wkb; ca.d[2] = wvb; ca.d[3] = wpb;
  cvt4<<<dim3(256, 4), 256, 0, stream>>>(ca, (Cc * Cc) / 4);

  gemm_qk<<<dim3(Mm / 128, Cc / 128, 2), 256, 0, stream>>>(xb, wqb, wkb, bq, bk, rope, qb, kb);
  gemm_v<<<dim3(Mm / 128, Cc / 128), 256, 0, stream>>>(xb, wvb, bv, vt);

  attn_kernel<<<dim3(16, Bb * Hh), 256, 0, stream>>>(qb, kb, vt, att);

  gemm_proj<<<dim3(Mm / 128, Cc / 128), 256, 0, stream>>>(att, wpb, bp, (float*)d_out);
}